// Round 19
// baseline (94.796 us; speedup 1.0000x reference)
//
#include <hip/hip_runtime.h>
#include <math.h>

// (N,C,H,W) = (4,19,512,1024), f32 input, scalar f32 output.
// R19 = ABLATION round. Two load-only probes, identical instruction
// structure (19 batched float4 loads -> tree sum -> asm keep-alive),
// differing ONLY in address pattern:
//   probe_strided: the real per-pixel pattern, 19 loads at 2MB (2^21)
//                  channel stride -> identical low 21 addr bits.
//   probe_linear:  same total bytes, block-contiguous windows, 4KB stride.
// If strided/rep >> linear/rep -> power-of-2 stride pathology confirmed.
// Real R12 pass1/pass2 run after (unchanged, correct output).
#define NC 19
#define NN 4
#define HH 512
#define WW 1024
#define NBLK 512             // real pass1: 512 blk * 256 thr * 8 tiles * 2 px
#define TILES 8
#define NREP 32
#define COLS (2 * NC)
#define CSTRIDE 512
#define REPS_A 3
#define REPS_B 5

typedef float floatx2 __attribute__((ext_vector_type(2)));

// ---------- probe A: 2MB-strided (real) pattern, loads only ----------
__global__ __launch_bounds__(256) void probe_strided(const float* __restrict__ x) {
    const int tid = threadIdx.x;
    const int t    = blockIdx.x * 256 + tid;   // 0..524287
    const int w4   = t & 255;
    const int rest = t >> 8;
    const int h    = rest & 511;
    const int n    = rest >> 9;
    const size_t cs = (size_t)HH * WW;
    const float* base = x + ((size_t)(n * NC) * HH + h) * WW + (size_t)w4 * 4;

    float acc = 0.0f;
    #pragma unroll 1
    for (int rep = 0; rep < REPS_A; ++rep) {
        float4 v[NC];
        #pragma unroll
        for (int c = 0; c < NC; ++c)
            v[c] = *reinterpret_cast<const float4*>(base + (size_t)c * cs);
        asm volatile("" ::: "memory");
        #pragma unroll
        for (int c = 0; c < NC; ++c)
            acc += (v[c].x + v[c].y) + (v[c].z + v[c].w);
    }
    asm volatile("" :: "v"(acc));   // keep loads live (rule #17), no writes
}

// ---------- probe B: block-linear pattern, loads only ----------
__global__ __launch_bounds__(256) void probe_linear(const float* __restrict__ x) {
    const int tid = threadIdx.x;
    const float4* xb = reinterpret_cast<const float4*>(x);
    const size_t base = (size_t)blockIdx.x * (NC * 256);   // contiguous 19*4KB window

    float acc = 0.0f;
    #pragma unroll 1
    for (int rep = 0; rep < REPS_B; ++rep) {
        float4 v[NC];
        #pragma unroll
        for (int c = 0; c < NC; ++c)
            v[c] = xb[base + (size_t)c * 256 + tid];
        asm volatile("" ::: "memory");
        #pragma unroll
        for (int c = 0; c < NC; ++c)
            acc += (v[c].x + v[c].y) + (v[c].z + v[c].w);
    }
    asm volatile("" :: "v"(acc));
}

// ---------- real pass1 (R12 verbatim: best known, 44.3us total) ----------
__global__ __launch_bounds__(256) void msiw_pass1(const float* __restrict__ x,
                                                  float* __restrict__ ws) {
    __shared__ float s_acc[2][NREP][NC];
    const int tid = threadIdx.x;

    for (int i = tid; i < 2 * NREP * NC; i += 256) (&s_acc[0][0][0])[i] = 0.0f;
    __syncthreads();

    const size_t cs = (size_t)HH * WW;
    const int rep = tid & (NREP - 1);

    float buf[2][NC][2];

    #define TILE_BASE(r) ({                                                   \
        const int u    = (blockIdx.x * TILES + (r)) * 256 + tid;              \
        const int w2   = u & 511;                                             \
        const int rest = u >> 9;                                              \
        const int h    = rest & 511;                                          \
        const int n    = rest >> 9;                                           \
        ((size_t)(n * NC) * HH + h) * WW + (size_t)w2 * 2; })

    #define LOAD_TILE(r, B)                                                   \
        {                                                                     \
            const size_t base_ = TILE_BASE(r);                                \
            _Pragma("unroll")                                                 \
            for (int c = 0; c < NC; ++c) {                                    \
                const floatx2* p2 = reinterpret_cast<const floatx2*>(         \
                    x + base_ + (size_t)c * cs);                              \
                const floatx2 v = *p2;                                        \
                buf[B][c][0] = v.x; buf[B][c][1] = v.y;                       \
            }                                                                 \
        }

    #define COMPUTE_TILE(B)                                                   \
        {                                                                     \
            float Z0 = 0.f, Z1 = 0.f, Q0 = 0.f, Q1 = 0.f;                     \
            float m0 = buf[B][0][0], m1 = buf[B][0][1];                       \
            int   p0 = 0, p1 = 0;                                             \
            _Pragma("unroll")                                                 \
            for (int c = 0; c < NC; ++c) {                                    \
                const float x0 = buf[B][c][0], x1 = buf[B][c][1];             \
                const float e0 = __expf(x0), e1 = __expf(x1);                 \
                Z0 += e0; Z1 += e1;                                           \
                Q0 = fmaf(e0, e0, Q0); Q1 = fmaf(e1, e1, Q1);                 \
                if (c > 0) {                                                  \
                    if (x0 > m0) { m0 = x0; p0 = c; }                         \
                    if (x1 > m1) { m1 = x1; p1 = c; }                         \
                }                                                             \
            }                                                                 \
            atomicAdd(&s_acc[0][rep][p0], Q0 / (Z0 * Z0));                    \
            atomicAdd(&s_acc[1][rep][p0], 1.0f);                              \
            atomicAdd(&s_acc[0][rep][p1], Q1 / (Z1 * Z1));                    \
            atomicAdd(&s_acc[1][rep][p1], 1.0f);                              \
        }

    LOAD_TILE(0, 0);
    asm volatile("" ::: "memory");
    #pragma unroll
    for (int r = 0; r < TILES - 1; ++r) {
        LOAD_TILE(r + 1, (r + 1) & 1);
        asm volatile("" ::: "memory");
        COMPUTE_TILE(r & 1);
    }
    COMPUTE_TILE((TILES - 1) & 1);

    __syncthreads();
    if (tid < COLS) {
        const int a = (tid < NC) ? 0 : 1;
        const int c = (tid < NC) ? tid : (tid - NC);
        float acc = 0.0f;
        #pragma unroll
        for (int rp = 0; rp < NREP; ++rp) acc += s_acc[a][rp][c];
        ws[(size_t)tid * CSTRIDE + blockIdx.x] = acc;
    }
}

__global__ __launch_bounds__(1024) void msiw_pass2(const float* __restrict__ ws,
                                                   float* __restrict__ out) {
    __shared__ float s_col[COLS];
    const int tid  = threadIdx.x;
    const int wv   = tid >> 6;
    const int lane = tid & 63;

    for (int col = wv; col < COLS; col += 16) {
        const float4* q = reinterpret_cast<const float4*>(ws + (size_t)col * CSTRIDE);
        float4 a[2];
        #pragma unroll
        for (int i = 0; i < 2; ++i) a[i] = q[lane + i * 64];
        float acc = 0.0f;
        #pragma unroll
        for (int i = 0; i < 2; ++i) acc += (a[i].x + a[i].y) + (a[i].z + a[i].w);
        #pragma unroll
        for (int off = 32; off > 0; off >>= 1) acc += __shfl_down(acc, off);
        if (lane == 0) s_col[col] = acc;
    }
    __syncthreads();

    if (tid == 0) {
        const double np_pow = pow((double)NN * HH * WW, 0.8);
        double total = 0.0;
        for (int c = 0; c < NC; ++c) {
            double den = pow((double)s_col[NC + c], 0.2) * np_pow;
            if (den < 1.0) den = 1.0;
            total += (double)s_col[c] / den;
        }
        out[0] = (float)(-total / (double)(NN * NC));
    }
}

extern "C" void kernel_launch(void* const* d_in, const int* in_sizes, int n_in,
                              void* d_out, int out_size, void* d_ws, size_t ws_size,
                              hipStream_t stream) {
    const float* x = (const float*)d_in[0];
    float* ws = (float*)d_ws;
    float* out = (float*)d_out;

    probe_strided<<<2048, 256, 0, stream>>>(x);
    probe_linear<<<2048, 256, 0, stream>>>(x);
    msiw_pass1<<<NBLK, 256, 0, stream>>>(x, ws);
    msiw_pass2<<<1, 1024, 0, stream>>>(ws, out);
}